// Round 2
// baseline (1252.449 us; speedup 1.0000x reference)
//
#include <hip/hip_runtime.h>
#include <stdint.h>

#define E_ 8
#define H_ 2048
#define I_ 4096
#define T_ 1024
#define N1_ (2 * I_) /* 8192 */

typedef unsigned short ushort_t;
typedef __bf16 bf16;
typedef __attribute__((ext_vector_type(8))) __bf16 bf16x8;
typedef __attribute__((ext_vector_type(4))) float f32x4;

// ---- fp32 -> bf16 round-half-up ----
__device__ __forceinline__ ushort_t f2bf(float f) {
    return (ushort_t)((__float_as_uint(f) + 0x8000u) >> 16);
}
// pack two fp32 -> two bf16 in one dword (a -> low ushort, b -> high)
__device__ __forceinline__ uint32_t pk2bf(float a, float b) {
    uint32_t ua = __float_as_uint(a) + 0x8000u;
    uint32_t ub = __float_as_uint(b) + 0x8000u;
    return __builtin_amdgcn_perm(ub, ua, 0x07060302u);
}

// ---- dequant one packed byte (int32 word, 2 fp4 codes) -> 2 scaled bf16 in a dword ----
// bf16 magnitudes for codes 0..7 = {0,.5,1,1.5,2,3,4,6}
__device__ __forceinline__ uint32_t dq_pair(uint32_t w, float s) {
    const uint32_t LO_HI = 0xC0804000u, LO_LO = 0xC0800000u;
    const uint32_t HI_HI = 0x40404040u, HI_LO = 0x3F3F3F00u;
    uint32_t sel = (w & 0x7u) | ((w & 0x70u) << 4);       // byte0=c0&7, byte1=c1&7
    uint32_t lo  = __builtin_amdgcn_perm(LO_HI, LO_LO, sel);
    uint32_t hi  = __builtin_amdgcn_perm(HI_HI, HI_LO, sel);
    uint32_t pair = __builtin_amdgcn_perm(hi, lo, 0x05010400u); // [lo0,hi0,lo1,hi1]
    pair |= ((w & 8u) << 12) | ((w & 0x80u) << 24);       // sign bits -> bit15/bit31
    uint32_t b0 = __float_as_uint(__uint_as_float(pair << 16) * s) + 0x8000u;
    uint32_t b1 = __float_as_uint(__uint_as_float(pair & 0xFFFF0000u) * s) + 0x8000u;
    return __builtin_amdgcn_perm(b1, b0, 0x07060302u);    // [bf(v0), bf(v1)]
}

// ==================== GEMM1: x(fp32) @ dequant(Wgu) + silu fusion ====================
// grid (I/64, T/128, C): x = 64-col tile of I (gate & up both), y = 128-row tile, z = chunk-local expert
__global__ __launch_bounds__(256, 2) void gemm1_kernel(
    const float* __restrict__ x,       // [E*T, H] fp32
    const int* __restrict__ gup,       // [E, H/2, 2I] packed bytes
    const float* __restrict__ gus,     // [E, H/16, 2I]
    const float* __restrict__ gscale_p,
    ushort_t* __restrict__ inter,      // chunk-local [C, T, I] bf16
    int e0) {
    __shared__ __align__(16) ushort_t As[128 * 32];
    __shared__ __align__(16) ushort_t Bs[128 * 40];   // rows: 0-63 gate, 64-127 up; +8 pad

    const int tid = threadIdx.x;
    const int lane = tid & 63, wv = tid >> 6;
    const int quad = lane >> 4, c16 = lane & 15;
    const int zloc = blockIdx.z, e = e0 + zloc;
    const int mBase = blockIdx.y * 128, nBlk = blockIdx.x;
    const float gsc = gscale_p[0];

    // B staging: thread -> (column bn, k-group kg); 8 packed rows each
    const int bn = tid & 127, kg = tid >> 7;
    const int colg = nBlk * 64 + (bn & 63) + ((bn >> 6) << 12); // up half offset +4096
    const int* bptr = gup + (size_t)e * (H_ / 2) * N1_ + (size_t)(kg * 8) * N1_ + colg;
    const float* sptr = gus + (size_t)e * (H_ / 16) * N1_ + (size_t)kg * N1_ + colg;
    uint4* bs_row = (uint4*)(&Bs[bn * 40]);

    // A staging: thread -> (row srow, 16-float half skh); fp32 load + bf16 pack
    const int srow = tid >> 1, skh = tid & 1;
    const float* agp = x + (size_t)(e * T_ + mBase + srow) * H_ + skh * 16;
    uint4* asw = (uint4*)(&As[srow * 32 + skh * 16]);

    f32x4 accg[2][4], accu[2][4];
    const f32x4 z4 = {0.f, 0.f, 0.f, 0.f};
#pragma unroll
    for (int i = 0; i < 2; ++i)
#pragma unroll
        for (int j = 0; j < 4; ++j) { accg[i][j] = z4; accu[i][j] = z4; }

    for (int kt = 0; kt < H_ / 32; ++kt) {
        // A tile loads (fp32)
        const float4* ag = (const float4*)(agp + kt * 32);
        float4 f0 = ag[0], f1 = ag[1], f2 = ag[2], f3 = ag[3];
        // B tile loads (packed fp4)
        int wt[8];
#pragma unroll
        for (int i = 0; i < 8; ++i) wt[i] = bptr[(size_t)i * N1_];
        float s = sptr[0] * gsc;

        uint4 a0, a1;
        a0.x = pk2bf(f0.x, f0.y); a0.y = pk2bf(f0.z, f0.w);
        a0.z = pk2bf(f1.x, f1.y); a0.w = pk2bf(f1.z, f1.w);
        a1.x = pk2bf(f2.x, f2.y); a1.y = pk2bf(f2.z, f2.w);
        a1.z = pk2bf(f3.x, f3.y); a1.w = pk2bf(f3.z, f3.w);
        asw[0] = a0; asw[1] = a1;

        uint4 q0, q1;
        q0.x = dq_pair((uint32_t)wt[0], s); q0.y = dq_pair((uint32_t)wt[1], s);
        q0.z = dq_pair((uint32_t)wt[2], s); q0.w = dq_pair((uint32_t)wt[3], s);
        q1.x = dq_pair((uint32_t)wt[4], s); q1.y = dq_pair((uint32_t)wt[5], s);
        q1.z = dq_pair((uint32_t)wt[6], s); q1.w = dq_pair((uint32_t)wt[7], s);
        bs_row[kg * 2] = q0;
        bs_row[kg * 2 + 1] = q1;

        bptr += (size_t)16 * N1_;
        sptr += (size_t)2 * N1_;
        __syncthreads();

        bf16x8 af0 = *(const bf16x8*)(&As[(wv * 32 + c16) * 32 + quad * 8]);
        bf16x8 af1 = *(const bf16x8*)(&As[(wv * 32 + 16 + c16) * 32 + quad * 8]);
#pragma unroll
        for (int nt = 0; nt < 4; ++nt) {
            bf16x8 bg = *(const bf16x8*)(&Bs[(nt * 16 + c16) * 40 + quad * 8]);
            bf16x8 bu = *(const bf16x8*)(&Bs[(64 + nt * 16 + c16) * 40 + quad * 8]);
            accg[0][nt] = __builtin_amdgcn_mfma_f32_16x16x32_bf16(af0, bg, accg[0][nt], 0, 0, 0);
            accg[1][nt] = __builtin_amdgcn_mfma_f32_16x16x32_bf16(af1, bg, accg[1][nt], 0, 0, 0);
            accu[0][nt] = __builtin_amdgcn_mfma_f32_16x16x32_bf16(af0, bu, accu[0][nt], 0, 0, 0);
            accu[1][nt] = __builtin_amdgcn_mfma_f32_16x16x32_bf16(af1, bu, accu[1][nt], 0, 0, 0);
        }
        __syncthreads();
    }

    // epilogue: inter = up * silu(gate), bf16
    ushort_t* ip = inter + (size_t)zloc * T_ * I_;
    const int colBase = nBlk * 64;
#pragma unroll
    for (int rt = 0; rt < 2; ++rt)
#pragma unroll
        for (int nt = 0; nt < 4; ++nt)
#pragma unroll
            for (int r = 0; r < 4; ++r) {
                int row = mBase + wv * 32 + rt * 16 + quad * 4 + r;
                int col = colBase + nt * 16 + c16;
                float g = accg[rt][nt][r];
                float u = accu[rt][nt][r];
                float v = u * g / (1.f + __expf(-g));
                ip[(size_t)row * I_ + col] = f2bf(v);
            }
}

// ==================== GEMM2: inter(bf16) @ dequant(Wd) -> out fp32 ====================
// grid (H/128, T/128, C)
__global__ __launch_bounds__(256, 2) void gemm2_kernel(
    const ushort_t* __restrict__ inter, // chunk-local [C, T, I] bf16
    const int* __restrict__ dp,         // [E, I/2, H]
    const float* __restrict__ dsc,      // [E, I/16, H]
    const float* __restrict__ gscale_p,
    float* __restrict__ out,            // [E*T, H] fp32
    int e0) {
    __shared__ __align__(16) ushort_t As[128 * 32];
    __shared__ __align__(16) ushort_t Bs[128 * 40];

    const int tid = threadIdx.x;
    const int lane = tid & 63, wv = tid >> 6;
    const int quad = lane >> 4, c16 = lane & 15;
    const int zloc = blockIdx.z, e = e0 + zloc;
    const int mBase = blockIdx.y * 128, nBase = blockIdx.x * 128;
    const float gsc = gscale_p[0];

    const int bn = tid & 127, kg = tid >> 7;
    const int colg = nBase + bn;
    const int* bptr = dp + (size_t)e * (I_ / 2) * H_ + (size_t)(kg * 8) * H_ + colg;
    const float* sptr = dsc + (size_t)e * (I_ / 16) * H_ + (size_t)kg * H_ + colg;
    uint4* bs_row = (uint4*)(&Bs[bn * 40]);

    const int srow = tid >> 1, skh = tid & 1;
    const ushort_t* agp = inter + (size_t)(zloc * T_ + mBase + srow) * I_ + skh * 16;
    uint4* asw = (uint4*)(&As[srow * 32 + skh * 16]);

    f32x4 acc[2][8];
    const f32x4 z4 = {0.f, 0.f, 0.f, 0.f};
#pragma unroll
    for (int i = 0; i < 2; ++i)
#pragma unroll
        for (int j = 0; j < 8; ++j) acc[i][j] = z4;

    for (int kt = 0; kt < I_ / 32; ++kt) {
        const uint4* ag = (const uint4*)(agp + kt * 32);
        uint4 v0 = ag[0], v1 = ag[1];
        int wt[8];
#pragma unroll
        for (int i = 0; i < 8; ++i) wt[i] = bptr[(size_t)i * H_];
        float s = sptr[0] * gsc;

        asw[0] = v0; asw[1] = v1;

        uint4 q0, q1;
        q0.x = dq_pair((uint32_t)wt[0], s); q0.y = dq_pair((uint32_t)wt[1], s);
        q0.z = dq_pair((uint32_t)wt[2], s); q0.w = dq_pair((uint32_t)wt[3], s);
        q1.x = dq_pair((uint32_t)wt[4], s); q1.y = dq_pair((uint32_t)wt[5], s);
        q1.z = dq_pair((uint32_t)wt[6], s); q1.w = dq_pair((uint32_t)wt[7], s);
        bs_row[kg * 2] = q0;
        bs_row[kg * 2 + 1] = q1;

        bptr += (size_t)16 * H_;
        sptr += (size_t)2 * H_;
        __syncthreads();

        bf16x8 af0 = *(const bf16x8*)(&As[(wv * 32 + c16) * 32 + quad * 8]);
        bf16x8 af1 = *(const bf16x8*)(&As[(wv * 32 + 16 + c16) * 32 + quad * 8]);
#pragma unroll
        for (int nt = 0; nt < 8; ++nt) {
            bf16x8 bfv = *(const bf16x8*)(&Bs[(nt * 16 + c16) * 40 + quad * 8]);
            acc[0][nt] = __builtin_amdgcn_mfma_f32_16x16x32_bf16(af0, bfv, acc[0][nt], 0, 0, 0);
            acc[1][nt] = __builtin_amdgcn_mfma_f32_16x16x32_bf16(af1, bfv, acc[1][nt], 0, 0, 0);
        }
        __syncthreads();
    }

#pragma unroll
    for (int rt = 0; rt < 2; ++rt)
#pragma unroll
        for (int nt = 0; nt < 8; ++nt)
#pragma unroll
            for (int r = 0; r < 4; ++r) {
                int row = mBase + wv * 32 + rt * 16 + quad * 4 + r;
                int col = nBase + nt * 16 + c16;
                out[(size_t)(e * T_ + row) * H_ + col] = acc[rt][nt][r];
            }
}

extern "C" void kernel_launch(void* const* d_in, const int* in_sizes, int n_in,
                              void* d_out, int out_size, void* d_ws, size_t ws_size,
                              hipStream_t stream) {
    const float* x = (const float*)d_in[0];
    const int* gup = (const int*)d_in[1];
    const float* gus = (const float*)d_in[2];
    const float* gug = (const float*)d_in[3];
    const int* dp = (const int*)d_in[4];
    const float* dsc = (const float*)d_in[5];
    const float* dg = (const float*)d_in[6];
    float* out = (float*)d_out;
    ushort_t* inter = (ushort_t*)d_ws;

    // workspace-aware expert chunking: need C * T*I * 2 bytes of scratch
    const size_t per_e = (size_t)T_ * I_ * 2;   // 8 MiB per expert
    int C = 8;
    if (ws_size < 8 * per_e) C = (ws_size >= 4 * per_e) ? 4 : (ws_size >= 2 * per_e) ? 2 : 1;

    for (int e0 = 0; e0 < E_; e0 += C) {
        gemm1_kernel<<<dim3(I_ / 64, T_ / 128, C), 256, 0, stream>>>(x, gup, gus, gug, inter, e0);
        gemm2_kernel<<<dim3(H_ / 128, T_ / 128, C), 256, 0, stream>>>(inter, dp, dsc, dg, out, e0);
    }
}

// Round 3
// 1023.110 us; speedup vs baseline: 1.2242x; 1.2242x over previous
//
#include <hip/hip_runtime.h>
#include <stdint.h>

#define E_ 8
#define H_ 2048
#define I_ 4096
#define T_ 1024
#define N1_ (2 * I_) /* 8192 */

typedef unsigned short ushort_t;
typedef __attribute__((ext_vector_type(8))) __bf16 bf16x8;
typedef __attribute__((ext_vector_type(4))) float f32x4;

// ---- fp32 -> bf16 round-half-up ----
__device__ __forceinline__ ushort_t f2bf(float f) {
    return (ushort_t)((__float_as_uint(f) + 0x8000u) >> 16);
}
// pack two fp32 -> two bf16 in one dword (a -> low ushort, b -> high)
__device__ __forceinline__ uint32_t pk2bf(float a, float b) {
    uint32_t ua = __float_as_uint(a) + 0x8000u;
    uint32_t ub = __float_as_uint(b) + 0x8000u;
    return __builtin_amdgcn_perm(ub, ua, 0x07060302u);
}

// ---- dequant one packed byte (int32 word, 2 fp4 codes) -> 2 scaled bf16 in a dword ----
// bf16 magnitudes for codes 0..7 = {0,.5,1,1.5,2,3,4,6}
__device__ __forceinline__ uint32_t dq_pair(uint32_t w, float s) {
    const uint32_t LO_HI = 0xC0804000u, LO_LO = 0xC0800000u;
    const uint32_t HI_HI = 0x40404040u, HI_LO = 0x3F3F3F00u;
    uint32_t sel = (w & 0x7u) | ((w & 0x70u) << 4);       // byte0=c0&7, byte1=c1&7
    uint32_t lo  = __builtin_amdgcn_perm(LO_HI, LO_LO, sel);
    uint32_t hi  = __builtin_amdgcn_perm(HI_HI, HI_LO, sel);
    uint32_t pair = __builtin_amdgcn_perm(hi, lo, 0x05010400u); // [lo0,hi0,lo1,hi1]
    pair |= ((w & 8u) << 12) | ((w & 0x80u) << 24);       // sign bits -> bit15/bit31
    uint32_t b0 = __float_as_uint(__uint_as_float(pair << 16) * s) + 0x8000u;
    uint32_t b1 = __float_as_uint(__uint_as_float(pair & 0xFFFF0000u) * s) + 0x8000u;
    return __builtin_amdgcn_perm(b1, b0, 0x07060302u);    // [bf(v0), bf(v1)]
}

// ==================== GEMM1: x(fp32) @ dequant(Wgu) + silu fusion ====================
// 512 threads, BM=256 (M rows), tile covers 64 I-cols (64 gate + 64 up N1-cols).
// 8 waves as 4(M) x 2(N): wave tile = 64 rows x (32 gate + 32 up cols).
// grid (I/64, T/256, C)
__global__ __launch_bounds__(512, 4) void gemm1_kernel(
    const float* __restrict__ x,       // [E*T, H] fp32
    const int* __restrict__ gup,       // [E, H/2, 2I] packed bytes
    const float* __restrict__ gus,     // [E, H/16, 2I]
    const float* __restrict__ gscale_p,
    ushort_t* __restrict__ inter,      // chunk-local [C, T, I] bf16
    int e0) {
    __shared__ __align__(16) ushort_t As[256 * 40];   // 256 rows x 32 k, pad->40
    __shared__ __align__(16) ushort_t Bs[128 * 40];   // rows 0-63 gate, 64-127 up

    const int tid = threadIdx.x;
    const int lane = tid & 63, wv = tid >> 6;
    const int quad = lane >> 4, c16 = lane & 15;
    const int mw = wv >> 1, nw = wv & 1;
    const int zloc = blockIdx.z, e = e0 + zloc;
    const int mBase = blockIdx.y * 256, nTile = blockIdx.x;
    const float gsc = gscale_p[0];

    // B staging: thread -> (N1-col bn of 128, k-quarter kq); 4 packed words each
    const int bn = tid & 127, kq = tid >> 7;
    const int colg = nTile * 64 + (bn & 63) + ((bn >> 6) << 12); // up half +4096
    const int* bptr = gup + (size_t)e * (H_ / 2) * N1_ + (size_t)(kq * 4) * N1_ + colg;
    const float* sptr = gus + (size_t)e * (H_ / 16) * N1_ + (size_t)(kq >> 1) * N1_ + colg;
    uint4* bs_w = (uint4*)(&Bs[bn * 40 + kq * 8]);

    // A staging: 4 passes; thread -> (row tid>>3 + p*64, 16B seg tid&7)
    const int arow = tid >> 3, seg = tid & 7;
    const float* ap = x + (size_t)(e * T_ + mBase + arow) * H_ + seg * 4;

    f32x4 accg[4][2], accu[4][2];
    const f32x4 z4 = {0.f, 0.f, 0.f, 0.f};
#pragma unroll
    for (int f = 0; f < 4; ++f)
#pragma unroll
        for (int b = 0; b < 2; ++b) { accg[f][b] = z4; accu[f][b] = z4; }

    for (int kt = 0; kt < H_ / 32; ++kt) {
        float4 fa[4];
#pragma unroll
        for (int p = 0; p < 4; ++p)
            fa[p] = *(const float4*)(ap + (size_t)(p * 64) * H_ + kt * 32);
        int wt[4];
#pragma unroll
        for (int i = 0; i < 4; ++i) wt[i] = bptr[(size_t)i * N1_];
        float s = sptr[0] * gsc;

#pragma unroll
        for (int p = 0; p < 4; ++p) {
            uint2 d;
            d.x = pk2bf(fa[p].x, fa[p].y);
            d.y = pk2bf(fa[p].z, fa[p].w);
            *(uint2*)(&As[(arow + p * 64) * 40 + seg * 4]) = d;
        }
        uint4 q;
        q.x = dq_pair((uint32_t)wt[0], s); q.y = dq_pair((uint32_t)wt[1], s);
        q.z = dq_pair((uint32_t)wt[2], s); q.w = dq_pair((uint32_t)wt[3], s);
        *bs_w = q;

        bptr += (size_t)16 * N1_;
        sptr += (size_t)2 * N1_;
        __syncthreads();

        bf16x8 bg0 = *(const bf16x8*)(&Bs[(nw * 32 + c16) * 40 + quad * 8]);
        bf16x8 bg1 = *(const bf16x8*)(&Bs[(nw * 32 + 16 + c16) * 40 + quad * 8]);
        bf16x8 bu0 = *(const bf16x8*)(&Bs[(64 + nw * 32 + c16) * 40 + quad * 8]);
        bf16x8 bu1 = *(const bf16x8*)(&Bs[(64 + nw * 32 + 16 + c16) * 40 + quad * 8]);
#pragma unroll
        for (int f = 0; f < 4; ++f) {
            bf16x8 af = *(const bf16x8*)(&As[(mw * 64 + f * 16 + c16) * 40 + quad * 8]);
            accg[f][0] = __builtin_amdgcn_mfma_f32_16x16x32_bf16(af, bg0, accg[f][0], 0, 0, 0);
            accg[f][1] = __builtin_amdgcn_mfma_f32_16x16x32_bf16(af, bg1, accg[f][1], 0, 0, 0);
            accu[f][0] = __builtin_amdgcn_mfma_f32_16x16x32_bf16(af, bu0, accu[f][0], 0, 0, 0);
            accu[f][1] = __builtin_amdgcn_mfma_f32_16x16x32_bf16(af, bu1, accu[f][1], 0, 0, 0);
        }
        __syncthreads();
    }

    // epilogue: inter = up * silu(gate), bf16
    ushort_t* ip = inter + (size_t)zloc * T_ * I_;
#pragma unroll
    for (int f = 0; f < 4; ++f)
#pragma unroll
        for (int b = 0; b < 2; ++b)
#pragma unroll
            for (int r = 0; r < 4; ++r) {
                int row = mBase + mw * 64 + f * 16 + quad * 4 + r;
                int col = nTile * 64 + nw * 32 + b * 16 + c16;
                float g = accg[f][b][r];
                float u = accu[f][b][r];
                float v = u * g / (1.f + __expf(-g));
                ip[(size_t)row * I_ + col] = f2bf(v);
            }
}

// ==================== GEMM2: inter(bf16) @ dequant(Wd) -> out fp32 ====================
// 512 threads, BM=256, BN=128. 8 waves as 4(M) x 2(N): wave tile 64x64.
// grid (H/128, T/256, C)
__global__ __launch_bounds__(512, 4) void gemm2_kernel(
    const ushort_t* __restrict__ inter, // chunk-local [C, T, I] bf16
    const int* __restrict__ dp,         // [E, I/2, H]
    const float* __restrict__ dsc,      // [E, I/16, H]
    const float* __restrict__ gscale_p,
    float* __restrict__ out,            // [E*T, H] fp32
    int e0) {
    __shared__ __align__(16) ushort_t As[256 * 40];
    __shared__ __align__(16) ushort_t Bs[128 * 40];

    const int tid = threadIdx.x;
    const int lane = tid & 63, wv = tid >> 6;
    const int quad = lane >> 4, c16 = lane & 15;
    const int mw = wv >> 1, nw = wv & 1;
    const int zloc = blockIdx.z, e = e0 + zloc;
    const int mBase = blockIdx.y * 256, nBase = blockIdx.x * 128;
    const float gsc = gscale_p[0];

    const int bn = tid & 127, kq = tid >> 7;
    const int col = nBase + bn;
    const int* bptr = dp + (size_t)e * (I_ / 2) * H_ + (size_t)(kq * 4) * H_ + col;
    const float* sptr = dsc + (size_t)e * (I_ / 16) * H_ + (size_t)(kq >> 1) * H_ + col;
    uint4* bs_w = (uint4*)(&Bs[bn * 40 + kq * 8]);

    // A staging: 2 passes; thread -> (row tid>>2 + p*128, 16B seg tid&3)
    const int arow = tid >> 2, seg = tid & 3;
    const ushort_t* ap = inter + (size_t)(zloc * T_ + mBase + arow) * I_ + seg * 8;

    f32x4 acc[4][4];
    const f32x4 z4 = {0.f, 0.f, 0.f, 0.f};
#pragma unroll
    for (int f = 0; f < 4; ++f)
#pragma unroll
        for (int b = 0; b < 4; ++b) acc[f][b] = z4;

    for (int kt = 0; kt < I_ / 32; ++kt) {
        uint4 va[2];
#pragma unroll
        for (int p = 0; p < 2; ++p)
            va[p] = *(const uint4*)(ap + (size_t)(p * 128) * I_ + kt * 32);
        int wt[4];
#pragma unroll
        for (int i = 0; i < 4; ++i) wt[i] = bptr[(size_t)i * H_];
        float s = sptr[0] * gsc;

#pragma unroll
        for (int p = 0; p < 2; ++p)
            *(uint4*)(&As[(arow + p * 128) * 40 + seg * 8]) = va[p];
        uint4 q;
        q.x = dq_pair((uint32_t)wt[0], s); q.y = dq_pair((uint32_t)wt[1], s);
        q.z = dq_pair((uint32_t)wt[2], s); q.w = dq_pair((uint32_t)wt[3], s);
        *bs_w = q;

        bptr += (size_t)16 * H_;
        sptr += (size_t)2 * H_;
        __syncthreads();

        bf16x8 bfr[4];
#pragma unroll
        for (int b = 0; b < 4; ++b)
            bfr[b] = *(const bf16x8*)(&Bs[(nw * 64 + b * 16 + c16) * 40 + quad * 8]);
#pragma unroll
        for (int f = 0; f < 4; ++f) {
            bf16x8 af = *(const bf16x8*)(&As[(mw * 64 + f * 16 + c16) * 40 + quad * 8]);
#pragma unroll
            for (int b = 0; b < 4; ++b)
                acc[f][b] = __builtin_amdgcn_mfma_f32_16x16x32_bf16(af, bfr[b], acc[f][b], 0, 0, 0);
        }
        __syncthreads();
    }

#pragma unroll
    for (int f = 0; f < 4; ++f)
#pragma unroll
        for (int b = 0; b < 4; ++b)
#pragma unroll
            for (int r = 0; r < 4; ++r) {
                int row = mBase + mw * 64 + f * 16 + quad * 4 + r;
                int c = nBase + nw * 64 + b * 16 + c16;
                out[(size_t)(e * T_ + row) * H_ + c] = acc[f][b][r];
            }
}

extern "C" void kernel_launch(void* const* d_in, const int* in_sizes, int n_in,
                              void* d_out, int out_size, void* d_ws, size_t ws_size,
                              hipStream_t stream) {
    const float* x = (const float*)d_in[0];
    const int* gup = (const int*)d_in[1];
    const float* gus = (const float*)d_in[2];
    const float* gug = (const float*)d_in[3];
    const int* dp = (const int*)d_in[4];
    const float* dsc = (const float*)d_in[5];
    const float* dg = (const float*)d_in[6];
    float* out = (float*)d_out;
    ushort_t* inter = (ushort_t*)d_ws;

    const size_t per_e = (size_t)T_ * I_ * 2;   // 8 MiB per expert
    int C = 8;
    if (ws_size < 8 * per_e) C = (ws_size >= 4 * per_e) ? 4 : (ws_size >= 2 * per_e) ? 2 : 1;

    for (int e0 = 0; e0 < E_; e0 += C) {
        gemm1_kernel<<<dim3(I_ / 64, T_ / 256, C), 512, 0, stream>>>(x, gup, gus, gug, inter, e0);
        gemm2_kernel<<<dim3(H_ / 128, T_ / 256, C), 512, 0, stream>>>(inter, dp, dsc, dg, out, e0);
    }
}

// Round 5
// 1019.789 us; speedup vs baseline: 1.2281x; 1.0033x over previous
//
#include <hip/hip_runtime.h>
#include <stdint.h>

#define E_ 8
#define H_ 2048
#define I_ 4096
#define T_ 1024
#define N1_ (2 * I_) /* 8192 */

typedef unsigned short ushort_t;
typedef __attribute__((ext_vector_type(8))) __bf16 bf16x8;
typedef __attribute__((ext_vector_type(4))) float f32x4;

// ---- fp32 -> bf16 round-half-up ----
__device__ __forceinline__ ushort_t f2bf(float f) {
    return (ushort_t)((__float_as_uint(f) + 0x8000u) >> 16);
}
// pack two fp32 -> two bf16 in one dword (a -> low ushort, b -> high)
__device__ __forceinline__ uint32_t pk2bf(float a, float b) {
    uint32_t ua = __float_as_uint(a) + 0x8000u;
    uint32_t ub = __float_as_uint(b) + 0x8000u;
    return __builtin_amdgcn_perm(ub, ua, 0x07060302u);
}

// ---- dequant one packed byte (int32 word, 2 fp4 codes) -> 2 scaled bf16 in a dword ----
__device__ __forceinline__ uint32_t dq_pair(uint32_t w, float s) {
    const uint32_t LO_HI = 0xC0804000u, LO_LO = 0xC0800000u;
    const uint32_t HI_HI = 0x40404040u, HI_LO = 0x3F3F3F00u;
    uint32_t sel = (w & 0x7u) | ((w & 0x70u) << 4);
    uint32_t lo  = __builtin_amdgcn_perm(LO_HI, LO_LO, sel);
    uint32_t hi  = __builtin_amdgcn_perm(HI_HI, HI_LO, sel);
    uint32_t pair = __builtin_amdgcn_perm(hi, lo, 0x05010400u);
    pair |= ((w & 8u) << 12) | ((w & 0x80u) << 24);
    uint32_t b0 = __float_as_uint(__uint_as_float(pair << 16) * s) + 0x8000u;
    uint32_t b1 = __float_as_uint(__uint_as_float(pair & 0xFFFF0000u) * s) + 0x8000u;
    return __builtin_amdgcn_perm(b1, b0, 0x07060302u);
}

// ==================== GEMM1: x(fp32) @ dequant(Wgu) + silu, pipelined ====================
// 512 thr, BM=256, tile = 64 I-cols (gate+up). 8 waves 4Mx2N, wave 64x(32g+32u).
// grid (I/64, T/256, C)
__global__ __launch_bounds__(512, 4) void gemm1_kernel(
    const float* __restrict__ x,
    const int* __restrict__ gup,
    const float* __restrict__ gus,
    const float* __restrict__ gscale_p,
    ushort_t* __restrict__ inter,
    int e0) {
    __shared__ __align__(16) ushort_t As[2][256 * 40];
    __shared__ __align__(16) ushort_t Bs[2][128 * 40];

    const int tid = threadIdx.x;
    const int lane = tid & 63, wv = tid >> 6;
    const int quad = lane >> 4, c16 = lane & 15;
    const int mw = wv >> 1, nw = wv & 1;
    const int zloc = blockIdx.z, e = e0 + zloc;
    const int mBase = blockIdx.y * 256, nTile = blockIdx.x;
    const float gsc = gscale_p[0];

    const int bn = tid & 127, kq = tid >> 7;
    const int colg = nTile * 64 + (bn & 63) + ((bn >> 6) << 12);
    const int* bptr = gup + (size_t)e * (H_ / 2) * N1_ + (size_t)(kq * 4) * N1_ + colg;
    const float* sptr = gus + (size_t)e * (H_ / 16) * N1_ + (size_t)(kq >> 1) * N1_ + colg;

    const int arow = tid >> 3, seg = tid & 7;
    const float* ap = x + (size_t)(e * T_ + mBase + arow) * H_ + seg * 4;

    f32x4 accg[4][2], accu[4][2];
    const f32x4 z4 = {0.f, 0.f, 0.f, 0.f};
#pragma unroll
    for (int f = 0; f < 4; ++f)
#pragma unroll
        for (int b = 0; b < 2; ++b) { accg[f][b] = z4; accu[f][b] = z4; }

    float4 fa[4]; int wt[4]; float sv;
    // ---- prologue: tile 0 ----
#pragma unroll
    for (int p = 0; p < 4; ++p) fa[p] = *(const float4*)(ap + (size_t)(p * 64) * H_);
#pragma unroll
    for (int i = 0; i < 4; ++i) wt[i] = bptr[(size_t)i * N1_];
    sv = sptr[0] * gsc;
    {
#pragma unroll
        for (int p = 0; p < 4; ++p) {
            uint2 d; d.x = pk2bf(fa[p].x, fa[p].y); d.y = pk2bf(fa[p].z, fa[p].w);
            *(uint2*)(&As[0][(arow + p * 64) * 40 + seg * 4]) = d;
        }
        uint4 q;
        q.x = dq_pair((uint32_t)wt[0], sv); q.y = dq_pair((uint32_t)wt[1], sv);
        q.z = dq_pair((uint32_t)wt[2], sv); q.w = dq_pair((uint32_t)wt[3], sv);
        *(uint4*)(&Bs[0][bn * 40 + kq * 8]) = q;
    }
    __syncthreads();

    for (int kt = 0; kt < H_ / 32 - 1; ++kt) {
        const int cur = kt & 1, nxt = cur ^ 1;
        // ---- prefetch tile kt+1 into registers ----
#pragma unroll
        for (int p = 0; p < 4; ++p)
            fa[p] = *(const float4*)(ap + (size_t)(p * 64) * H_ + (kt + 1) * 32);
        const int* bp = bptr + (size_t)(kt + 1) * 16 * N1_;
#pragma unroll
        for (int i = 0; i < 4; ++i) wt[i] = bp[(size_t)i * N1_];
        sv = sptr[(size_t)(kt + 1) * 2 * N1_] * gsc;

        // ---- consume current LDS tile ----
        bf16x8 bg0 = *(const bf16x8*)(&Bs[cur][(nw * 32 + c16) * 40 + quad * 8]);
        bf16x8 bg1 = *(const bf16x8*)(&Bs[cur][(nw * 32 + 16 + c16) * 40 + quad * 8]);
        bf16x8 bu0 = *(const bf16x8*)(&Bs[cur][(64 + nw * 32 + c16) * 40 + quad * 8]);
        bf16x8 bu1 = *(const bf16x8*)(&Bs[cur][(64 + nw * 32 + 16 + c16) * 40 + quad * 8]);
#pragma unroll
        for (int f = 0; f < 4; ++f) {
            bf16x8 af = *(const bf16x8*)(&As[cur][(mw * 64 + f * 16 + c16) * 40 + quad * 8]);
            accg[f][0] = __builtin_amdgcn_mfma_f32_16x16x32_bf16(af, bg0, accg[f][0], 0, 0, 0);
            accg[f][1] = __builtin_amdgcn_mfma_f32_16x16x32_bf16(af, bg1, accg[f][1], 0, 0, 0);
            accu[f][0] = __builtin_amdgcn_mfma_f32_16x16x32_bf16(af, bu0, accu[f][0], 0, 0, 0);
            accu[f][1] = __builtin_amdgcn_mfma_f32_16x16x32_bf16(af, bu1, accu[f][1], 0, 0, 0);
        }

        // ---- stage prefetched tile into other buffer ----
#pragma unroll
        for (int p = 0; p < 4; ++p) {
            uint2 d; d.x = pk2bf(fa[p].x, fa[p].y); d.y = pk2bf(fa[p].z, fa[p].w);
            *(uint2*)(&As[nxt][(arow + p * 64) * 40 + seg * 4]) = d;
        }
        uint4 q;
        q.x = dq_pair((uint32_t)wt[0], sv); q.y = dq_pair((uint32_t)wt[1], sv);
        q.z = dq_pair((uint32_t)wt[2], sv); q.w = dq_pair((uint32_t)wt[3], sv);
        *(uint4*)(&Bs[nxt][bn * 40 + kq * 8]) = q;
        __syncthreads();
    }

    // ---- last tile (buffer 1) ----
    {
        const int cur = (H_ / 32 - 1) & 1;
        bf16x8 bg0 = *(const bf16x8*)(&Bs[cur][(nw * 32 + c16) * 40 + quad * 8]);
        bf16x8 bg1 = *(const bf16x8*)(&Bs[cur][(nw * 32 + 16 + c16) * 40 + quad * 8]);
        bf16x8 bu0 = *(const bf16x8*)(&Bs[cur][(64 + nw * 32 + c16) * 40 + quad * 8]);
        bf16x8 bu1 = *(const bf16x8*)(&Bs[cur][(64 + nw * 32 + 16 + c16) * 40 + quad * 8]);
#pragma unroll
        for (int f = 0; f < 4; ++f) {
            bf16x8 af = *(const bf16x8*)(&As[cur][(mw * 64 + f * 16 + c16) * 40 + quad * 8]);
            accg[f][0] = __builtin_amdgcn_mfma_f32_16x16x32_bf16(af, bg0, accg[f][0], 0, 0, 0);
            accg[f][1] = __builtin_amdgcn_mfma_f32_16x16x32_bf16(af, bg1, accg[f][1], 0, 0, 0);
            accu[f][0] = __builtin_amdgcn_mfma_f32_16x16x32_bf16(af, bu0, accu[f][0], 0, 0, 0);
            accu[f][1] = __builtin_amdgcn_mfma_f32_16x16x32_bf16(af, bu1, accu[f][1], 0, 0, 0);
        }
    }

    // epilogue: inter = up * silu(gate)
    ushort_t* ip = inter + (size_t)zloc * T_ * I_;
#pragma unroll
    for (int f = 0; f < 4; ++f)
#pragma unroll
        for (int b = 0; b < 2; ++b)
#pragma unroll
            for (int r = 0; r < 4; ++r) {
                int row = mBase + mw * 64 + f * 16 + quad * 4 + r;
                int col = nTile * 64 + nw * 32 + b * 16 + c16;
                float g = accg[f][b][r];
                float u = accu[f][b][r];
                float v = u * g / (1.f + __expf(-g));
                ip[(size_t)row * I_ + col] = f2bf(v);
            }
}

// ==================== GEMM2: inter(bf16) @ dequant(Wd) -> fp32, pipelined ====================
// 512 thr, BM=256, BN=128. 8 waves 4Mx2N, wave 64x64. grid (H/128, T/256, C)
__global__ __launch_bounds__(512, 4) void gemm2_kernel(
    const ushort_t* __restrict__ inter,
    const int* __restrict__ dp,
    const float* __restrict__ dsc,
    const float* __restrict__ gscale_p,
    float* __restrict__ out,
    int e0) {
    __shared__ __align__(16) ushort_t As[2][256 * 40];
    __shared__ __align__(16) ushort_t Bs[2][128 * 40];

    const int tid = threadIdx.x;
    const int lane = tid & 63, wv = tid >> 6;
    const int quad = lane >> 4, c16 = lane & 15;
    const int mw = wv >> 1, nw = wv & 1;
    const int zloc = blockIdx.z, e = e0 + zloc;
    const int mBase = blockIdx.y * 256, nBase = blockIdx.x * 128;
    const float gsc = gscale_p[0];

    const int bn = tid & 127, kq = tid >> 7;
    const int col = nBase + bn;
    const int* bptr = dp + (size_t)e * (I_ / 2) * H_ + (size_t)(kq * 4) * H_ + col;
    const float* sptr = dsc + (size_t)e * (I_ / 16) * H_ + (size_t)(kq >> 1) * H_ + col;

    const int arow = tid >> 2, seg = tid & 3;
    const ushort_t* ap = inter + (size_t)(zloc * T_ + mBase + arow) * I_ + seg * 8;

    f32x4 acc[4][4];
    const f32x4 z4 = {0.f, 0.f, 0.f, 0.f};
#pragma unroll
    for (int f = 0; f < 4; ++f)
#pragma unroll
        for (int b = 0; b < 4; ++b) acc[f][b] = z4;

    uint4 va[2]; int wt[4]; float sv;
    // ---- prologue: tile 0 ----
#pragma unroll
    for (int p = 0; p < 2; ++p) va[p] = *(const uint4*)(ap + (size_t)(p * 128) * I_);
#pragma unroll
    for (int i = 0; i < 4; ++i) wt[i] = bptr[(size_t)i * H_];
    sv = sptr[0] * gsc;
    {
#pragma unroll
        for (int p = 0; p < 2; ++p)
            *(uint4*)(&As[0][(arow + p * 128) * 40 + seg * 8]) = va[p];
        uint4 q;
        q.x = dq_pair((uint32_t)wt[0], sv); q.y = dq_pair((uint32_t)wt[1], sv);
        q.z = dq_pair((uint32_t)wt[2], sv); q.w = dq_pair((uint32_t)wt[3], sv);
        *(uint4*)(&Bs[0][bn * 40 + kq * 8]) = q;
    }
    __syncthreads();

    for (int kt = 0; kt < I_ / 32 - 1; ++kt) {
        const int cur = kt & 1, nxt = cur ^ 1;
        // ---- prefetch tile kt+1 ----
#pragma unroll
        for (int p = 0; p < 2; ++p)
            va[p] = *(const uint4*)(ap + (size_t)(p * 128) * I_ + (kt + 1) * 32);
        const int* bp = bptr + (size_t)(kt + 1) * 16 * H_;
#pragma unroll
        for (int i = 0; i < 4; ++i) wt[i] = bp[(size_t)i * H_];
        sv = sptr[(size_t)(kt + 1) * 2 * H_] * gsc;

        // ---- consume current ----
        bf16x8 bfr[4];
#pragma unroll
        for (int b = 0; b < 4; ++b)
            bfr[b] = *(const bf16x8*)(&Bs[cur][(nw * 64 + b * 16 + c16) * 40 + quad * 8]);
#pragma unroll
        for (int f = 0; f < 4; ++f) {
            bf16x8 af = *(const bf16x8*)(&As[cur][(mw * 64 + f * 16 + c16) * 40 + quad * 8]);
#pragma unroll
            for (int b = 0; b < 4; ++b)
                acc[f][b] = __builtin_amdgcn_mfma_f32_16x16x32_bf16(af, bfr[b], acc[f][b], 0, 0, 0);
        }

        // ---- stage next ----
#pragma unroll
        for (int p = 0; p < 2; ++p)
            *(uint4*)(&As[nxt][(arow + p * 128) * 40 + seg * 8]) = va[p];
        uint4 q;
        q.x = dq_pair((uint32_t)wt[0], sv); q.y = dq_pair((uint32_t)wt[1], sv);
        q.z = dq_pair((uint32_t)wt[2], sv); q.w = dq_pair((uint32_t)wt[3], sv);
        *(uint4*)(&Bs[nxt][bn * 40 + kq * 8]) = q;
        __syncthreads();
    }

    // ---- last tile ----
    {
        const int cur = (I_ / 32 - 1) & 1;
        bf16x8 bfr[4];
#pragma unroll
        for (int b = 0; b < 4; ++b)
            bfr[b] = *(const bf16x8*)(&Bs[cur][(nw * 64 + b * 16 + c16) * 40 + quad * 8]);
#pragma unroll
        for (int f = 0; f < 4; ++f) {
            bf16x8 af = *(const bf16x8*)(&As[cur][(mw * 64 + f * 16 + c16) * 40 + quad * 8]);
#pragma unroll
            for (int b = 0; b < 4; ++b)
                acc[f][b] = __builtin_amdgcn_mfma_f32_16x16x32_bf16(af, bfr[b], acc[f][b], 0, 0, 0);
        }
    }

#pragma unroll
    for (int f = 0; f < 4; ++f)
#pragma unroll
        for (int b = 0; b < 4; ++b)
#pragma unroll
            for (int r = 0; r < 4; ++r) {
                int row = mBase + mw * 64 + f * 16 + quad * 4 + r;
                int c = nBase + nw * 64 + b * 16 + c16;
                out[(size_t)(e * T_ + row) * H_ + c] = acc[f][b][r];
            }
}

extern "C" void kernel_launch(void* const* d_in, const int* in_sizes, int n_in,
                              void* d_out, int out_size, void* d_ws, size_t ws_size,
                              hipStream_t stream) {
    const float* x = (const float*)d_in[0];
    const int* gup = (const int*)d_in[1];
    const float* gus = (const float*)d_in[2];
    const float* gug = (const float*)d_in[3];
    const int* dp = (const int*)d_in[4];
    const float* dsc = (const float*)d_in[5];
    const float* dg = (const float*)d_in[6];
    float* out = (float*)d_out;
    ushort_t* inter = (ushort_t*)d_ws;

    const size_t per_e = (size_t)T_ * I_ * 2;
    int C = 8;
    if (ws_size < 8 * per_e) C = (ws_size >= 4 * per_e) ? 4 : (ws_size >= 2 * per_e) ? 2 : 1;

    for (int e0 = 0; e0 < E_; e0 += C) {
        gemm1_kernel<<<dim3(I_ / 64, T_ / 256, C), 512, 0, stream>>>(x, gup, gus, gug, inter, e0);
        gemm2_kernel<<<dim3(H_ / 128, T_ / 256, C), 512, 0, stream>>>(inter, dp, dsc, dg, out, e0);
    }
}